// Round 12
// baseline (239.397 us; speedup 1.0000x reference)
//
#include <hip/hip_runtime.h>

// x: (B=4, C=64, H=512, W=512) fp32 -> 131072 independent rows of 512 cols.
// FIR: f[j] = sum_k a[k]*x[j-2+k] (SAME zero-pad), then IIR:
//   y[j] = f[j] - (v0*y[j-3] + v1*y[j-2] + v2*y[j-1]), zero initial state.
//
// R12 = R11 with the 64-shuffle store transpose replaced by an LDS bounce
// (8 DS ops/thread, bank-optimal via q-rotation). Stores keep the proven
// full-line wave footprint (2x512B contiguous per instruction).
//
//   thread = (row, 16-col segment); 8 rows x 32 segs = 256 threads/block.
//   loads : 6 direct float4 per thread (window cols 16s-4 .. 16s+19)
//   phase1: particular solution y_p over 16 cols (zero entry state)
//   scan  : Hillis-Steele affine scan over 32 segments per 32-lane group
//   fixup : y[k] += H[.][k] . s_enter   (H = 192B LDS, broadcast reads)
//   store : LDS transpose bounce -> 4 coalesced full-line float4 stores.

constexpr int Wd    = 512;
constexpr int TROWS = 8;
constexpr int NT    = 256;
constexpr int F4ROW = Wd / 4;   // 128

__global__ __launch_bounds__(NT, 6)
void iir_conv2d_kernel(const float4* __restrict__ x4,
                       const float* __restrict__ w1,   // (C,1,5)
                       const float* __restrict__ w2,   // (C,3)
                       float4* __restrict__ y4)
{
    __shared__ float4 lbuf[TROWS][F4ROW];   // 16 KB store-transpose bounce
    __shared__ float  H[3][16];             // y[k] response to unit entry state

    const int tid  = threadIdx.x;
    const int lane = tid & 63;
    const int r    = tid >> 5;          // row within block (0..7)
    const int s    = tid & 31;          // 16-col segment (0..31)
    const int row0 = blockIdx.x * TROWS;   // 8 | 512 -> channel uniform per block
    const int row  = row0 + r;
    const int c    = (row0 >> 9) & 63;

    // taps (wave-uniform, L1 broadcast)
    const float a0 = w1[c*5+0], a1 = w1[c*5+1], a2 = w1[c*5+2],
                a3 = w1[c*5+3], a4 = w1[c*5+4];
    const float v0 = w2[c*3+0], v1 = w2[c*3+1], v2 = w2[c*3+2];

    // ---- issue 6 direct float4 loads: cols 16s-4 .. 16s+19 of this row ----
    const float4* __restrict__ xr = x4 + (size_t)row * F4ROW;
    float4 xv[6];
    #pragma unroll
    for (int k = 0; k < 6; ++k) {
        const int g = 4*s - 1 + k;
        float4 t = {0.f, 0.f, 0.f, 0.f};
        if (g >= 0 && g < F4ROW) t = xr[g];   // OOB only at s=0 / s=31 edges
        xv[k] = t;
    }

    // ---- H table: 3 threads compute the 3 columns (16-step recursions) ----
    if (tid < 3) {
        const int j = tid;
        float h3 = (j==0) ? 1.f : 0.f;
        float h2 = (j==1) ? 1.f : 0.f;
        float h1 = (j==2) ? 1.f : 0.f;
        #pragma unroll
        for (int k = 0; k < 16; ++k) {
            const float n = -(v0*h3 + v1*h2 + v2*h1);
            H[j][k] = n;
            h3 = h2; h2 = h1; h1 = n;
        }
    }

    // ---- unpack window ----
    float xw[24];
    #pragma unroll
    for (int k = 0; k < 6; ++k) {
        xw[4*k+0] = xv[k].x; xw[4*k+1] = xv[k].y;
        xw[4*k+2] = xv[k].z; xw[4*k+3] = xv[k].w;
    }

    // ---- phase 1: particular solution (zero entry state) ----
    float y[16];
    {
        float ym3 = 0.f, ym2 = 0.f, ym1 = 0.f;
        #pragma unroll
        for (int k = 0; k < 16; ++k) {
            // col 16s+k needs x[col-2..col+2] = xw[k+2..k+6]
            const float f = a0*xw[k+2] + a1*xw[k+3] + a2*xw[k+4]
                          + a3*xw[k+5] + a4*xw[k+6];
            const float t = v0*ym3 + v1*ym2;      // off the serial chain
            const float yy = (f - t) - v2*ym1;
            y[k] = yy;
            ym3 = ym2; ym2 = ym1; ym1 = yy;
        }
    }

    __syncthreads();   // H ready

    // ---- T = 16-step state transform: T[i][j] = H[j][13+i] ----
    float M[3][3];
    #pragma unroll
    for (int i = 0; i < 3; ++i)
        #pragma unroll
        for (int j = 0; j < 3; ++j) M[i][j] = H[j][13+i];

    // ---- affine scan over 32 segments (within each 32-lane group) ----
    float b0 = y[13], b1 = y[14], b2 = y[15];
    #pragma unroll
    for (int rd = 0; rd < 5; ++rd) {
        const int d = 1 << rd;
        const int src = (s >= d) ? (lane - d) : lane;
        const float g0 = __shfl(b0, src, 64);
        const float g1 = __shfl(b1, src, 64);
        const float g2 = __shfl(b2, src, 64);
        if (s >= d) {
            b0 += M[0][0]*g0 + M[0][1]*g1 + M[0][2]*g2;
            b1 += M[1][0]*g0 + M[1][1]*g1 + M[1][2]*g2;
            b2 += M[2][0]*g0 + M[2][1]*g1 + M[2][2]*g2;
        }
        if (rd < 4) {   // M <- M*M for the next round
            float N[3][3];
            #pragma unroll
            for (int i = 0; i < 3; ++i)
                #pragma unroll
                for (int j = 0; j < 3; ++j)
                    N[i][j] = M[i][0]*M[0][j] + M[i][1]*M[1][j] + M[i][2]*M[2][j];
            #pragma unroll
            for (int i = 0; i < 3; ++i)
                #pragma unroll
                for (int j = 0; j < 3; ++j) M[i][j] = N[i][j];
        }
    }

    // ---- entering state = inclusive scan of previous segment; fixup ----
    {
        const int src = (s >= 1) ? (lane - 1) : lane;
        float s0 = __shfl(b0, src, 64);
        float s1 = __shfl(b1, src, 64);
        float s2 = __shfl(b2, src, 64);
        if (s == 0) { s0 = 0.f; s1 = 0.f; s2 = 0.f; }
        #pragma unroll
        for (int k = 0; k < 16; ++k)
            y[k] += H[0][k]*s0 + H[1][k]*s1 + H[2][k]*s2;
    }

    // ---- store transpose via LDS bounce ----
    // Write: f4 q of segment s at position 4s + ((q+s)&3): the fixed-q write
    // instruction covers all 32 banks exactly once per 32-lane half (minimal).
    #pragma unroll
    for (int q = 0; q < 4; ++q) {
        float4 o;
        o.x = y[4*q+0]; o.y = y[4*q+1]; o.z = y[4*q+2]; o.w = y[4*q+3];
        lbuf[r][4*s + ((q + s) & 3)] = o;
    }
    __syncthreads();

    // Read + store: lane i handles output f4 g=32u+i of its row; un-rotate.
    // Global store instruction = 2x512B contiguous (full lines), as in R11.
    float4* __restrict__ yrow = y4 + (size_t)row * F4ROW;
    #pragma unroll
    for (int u = 0; u < 4; ++u) {
        const int i  = lane & 31;
        const int g  = 32*u + i;
        const int sp = g >> 2;
        const int q0 = g & 3;
        yrow[g] = lbuf[r][4*sp + ((q0 + sp) & 3)];
    }
}

extern "C" void kernel_launch(void* const* d_in, const int* in_sizes, int n_in,
                              void* d_out, int out_size, void* d_ws, size_t ws_size,
                              hipStream_t stream) {
    const float4* x4 = (const float4*)d_in[0];
    const float*  w1 = (const float*)d_in[1];
    const float*  w2 = (const float*)d_in[2];
    float4* y4 = (float4*)d_out;

    const int nrows  = out_size / Wd;        // 131072
    const int blocks = nrows / TROWS;        // 16384
    iir_conv2d_kernel<<<blocks, NT, 0, stream>>>(x4, w1, w2, y4);
}

// Round 13
// 102.164 us; speedup vs baseline: 2.3432x; 2.3432x over previous
//
#include <hip/hip_runtime.h>

// x: (B=4, C=64, H=512, W=512) fp32 -> 131072 independent rows of 512 cols.
// FIR: f[j] = sum_k a[k]*x[j-2+k] (SAME zero-pad), then IIR:
//   y[j] = f[j] - (v0*y[j-3] + v1*y[j-2] + v2*y[j-1]), zero initial state.
//
// R13 = R11 (104us known-good) + ONE change: the homogeneous fixup is
// computed by running the feedback recursion in registers from the
// entering state (48 FMAs), instead of 48 LDS broadcast reads of H.
// H remains only to seed the 3x3 scan matrix M (9 reads).
// Store transpose keeps R11's proven full-line shuffle form.
//
//   thread = (row, 16-col segment); 8 rows x 32 segs = 256 threads/block.
//   loads : 6 direct float4 per thread (window cols 16s-4 .. 16s+19)
//   phase1: particular solution y_p over 16 cols (zero entry state)
//   scan  : Hillis-Steele affine scan over 32 segments per 32-lane group
//   fixup : w[k] recursion from s_enter, y[k] += w[k]   (no LDS)
//   stores: shuffle-transposed, 4 coalesced full-line float4 per thread.

constexpr int Wd    = 512;
constexpr int TROWS = 8;
constexpr int NT    = 256;
constexpr int F4ROW = Wd / 4;   // 128

__global__ __launch_bounds__(NT, 6)
void iir_conv2d_kernel(const float4* __restrict__ x4,
                       const float* __restrict__ w1,   // (C,1,5)
                       const float* __restrict__ w2,   // (C,3)
                       float4* __restrict__ y4)
{
    __shared__ float H[3][16];   // H[j][k]: y[k] response to unit entry state e_j

    const int tid  = threadIdx.x;
    const int lane = tid & 63;
    const int r    = tid >> 5;          // row within block (0..7)
    const int s    = tid & 31;          // 16-col segment (0..31)
    const int row0 = blockIdx.x * TROWS;   // 8 | 512 -> channel uniform per block
    const int row  = row0 + r;
    const int c    = (row0 >> 9) & 63;

    // taps (wave-uniform, L1 broadcast)
    const float a0 = w1[c*5+0], a1 = w1[c*5+1], a2 = w1[c*5+2],
                a3 = w1[c*5+3], a4 = w1[c*5+4];
    const float v0 = w2[c*3+0], v1 = w2[c*3+1], v2 = w2[c*3+2];

    // ---- issue 6 direct float4 loads: cols 16s-4 .. 16s+19 of this row ----
    const float4* __restrict__ xr = x4 + (size_t)row * F4ROW;
    float4 xv[6];
    #pragma unroll
    for (int k = 0; k < 6; ++k) {
        const int g = 4*s - 1 + k;
        float4 t = {0.f, 0.f, 0.f, 0.f};
        if (g >= 0 && g < F4ROW) t = xr[g];   // OOB only at s=0 / s=31 edges
        xv[k] = t;
    }

    // ---- H table: 3 threads compute the 3 columns (16-step recursions) ----
    if (tid < 3) {
        const int j = tid;
        float h3 = (j==0) ? 1.f : 0.f;
        float h2 = (j==1) ? 1.f : 0.f;
        float h1 = (j==2) ? 1.f : 0.f;
        #pragma unroll
        for (int k = 0; k < 16; ++k) {
            const float n = -(v0*h3 + v1*h2 + v2*h1);
            H[j][k] = n;
            h3 = h2; h2 = h1; h1 = n;
        }
    }

    // ---- unpack window ----
    float xw[24];
    #pragma unroll
    for (int k = 0; k < 6; ++k) {
        xw[4*k+0] = xv[k].x; xw[4*k+1] = xv[k].y;
        xw[4*k+2] = xv[k].z; xw[4*k+3] = xv[k].w;
    }

    // ---- phase 1: particular solution (zero entry state) ----
    float y[16];
    {
        float ym3 = 0.f, ym2 = 0.f, ym1 = 0.f;
        #pragma unroll
        for (int k = 0; k < 16; ++k) {
            // col 16s+k needs x[col-2..col+2] = xw[k+2..k+6]
            const float f = a0*xw[k+2] + a1*xw[k+3] + a2*xw[k+4]
                          + a3*xw[k+5] + a4*xw[k+6];
            const float t = v0*ym3 + v1*ym2;      // off the serial chain
            const float yy = (f - t) - v2*ym1;
            y[k] = yy;
            ym3 = ym2; ym2 = ym1; ym1 = yy;
        }
    }

    __syncthreads();   // H ready (the only barrier)

    // ---- T = 16-step state transform: T[i][j] = H[j][13+i] ----
    float M[3][3];
    #pragma unroll
    for (int i = 0; i < 3; ++i)
        #pragma unroll
        for (int j = 0; j < 3; ++j) M[i][j] = H[j][13+i];

    // ---- affine scan over 32 segments (within each 32-lane group) ----
    float b0 = y[13], b1 = y[14], b2 = y[15];
    #pragma unroll
    for (int rd = 0; rd < 5; ++rd) {
        const int d = 1 << rd;
        const int src = (s >= d) ? (lane - d) : lane;
        const float g0 = __shfl(b0, src, 64);
        const float g1 = __shfl(b1, src, 64);
        const float g2 = __shfl(b2, src, 64);
        if (s >= d) {
            b0 += M[0][0]*g0 + M[0][1]*g1 + M[0][2]*g2;
            b1 += M[1][0]*g0 + M[1][1]*g1 + M[1][2]*g2;
            b2 += M[2][0]*g0 + M[2][1]*g1 + M[2][2]*g2;
        }
        if (rd < 4) {   // M <- M*M for the next round
            float N[3][3];
            #pragma unroll
            for (int i = 0; i < 3; ++i)
                #pragma unroll
                for (int j = 0; j < 3; ++j)
                    N[i][j] = M[i][0]*M[0][j] + M[i][1]*M[1][j] + M[i][2]*M[2][j];
            #pragma unroll
            for (int i = 0; i < 3; ++i)
                #pragma unroll
                for (int j = 0; j < 3; ++j) M[i][j] = N[i][j];
        }
    }

    // ---- entering state = inclusive scan of previous segment ----
    // fixup via in-register recursion: w[k] = -(v0 w[k-3] + v1 w[k-2] + v2 w[k-1])
    // seeded with (wm3,wm2,wm1) = entering state; y[k] += w[k]. No LDS.
    {
        const int src = (s >= 1) ? (lane - 1) : lane;
        float wm3 = __shfl(b0, src, 64);
        float wm2 = __shfl(b1, src, 64);
        float wm1 = __shfl(b2, src, 64);
        if (s == 0) { wm3 = 0.f; wm2 = 0.f; wm1 = 0.f; }
        #pragma unroll
        for (int k = 0; k < 16; ++k) {
            const float w = -(v0*wm3 + v1*wm2 + v2*wm1);
            y[k] += w;
            wm3 = wm2; wm2 = wm1; wm1 = w;
        }
    }

    // ---- store: shuffle-transpose then coalesced full-line float4 stores ----
    // Instr u: lane i (i=lane&31) stores f4 idx 32u+i of its row
    //   -> floats 128u+4i+m, owned by src lane 8u+(i>>2), reg 4*(i&3)+m.
    // Sub-round over q=(i&3) keeps all register indices compile-time.
    float4* __restrict__ yrow = y4 + (size_t)row * F4ROW;
    #pragma unroll
    for (int u = 0; u < 4; ++u) {
        const int srcl = (lane & 32) | (8*u + ((lane & 31) >> 2));
        float out0, out1, out2, out3;
        #pragma unroll
        for (int q = 0; q < 4; ++q) {
            const float t0 = __shfl(y[4*q+0], srcl, 64);
            const float t1 = __shfl(y[4*q+1], srcl, 64);
            const float t2 = __shfl(y[4*q+2], srcl, 64);
            const float t3 = __shfl(y[4*q+3], srcl, 64);
            if ((lane & 3) == q) { out0 = t0; out1 = t1; out2 = t2; out3 = t3; }
        }
        float4 o; o.x = out0; o.y = out1; o.z = out2; o.w = out3;
        yrow[32*u + (lane & 31)] = o;
    }
}

extern "C" void kernel_launch(void* const* d_in, const int* in_sizes, int n_in,
                              void* d_out, int out_size, void* d_ws, size_t ws_size,
                              hipStream_t stream) {
    const float4* x4 = (const float4*)d_in[0];
    const float*  w1 = (const float*)d_in[1];
    const float*  w2 = (const float*)d_in[2];
    float4* y4 = (float4*)d_out;

    const int nrows  = out_size / Wd;        // 131072
    const int blocks = nrows / TROWS;        // 16384
    iir_conv2d_kernel<<<blocks, NT, 0, stream>>>(x4, w1, w2, y4);
}